// Round 5
// baseline (197.252 us; speedup 1.0000x reference)
//
#include <hip/hip_runtime.h>
#include <hip/hip_bf16.h>
#include <cstdint>
#include <cstddef>

typedef __attribute__((ext_vector_type(8))) short bf16x8;
typedef __attribute__((ext_vector_type(4))) float floatx4;
typedef __attribute__((ext_vector_type(16))) float floatx16;
typedef __attribute__((ext_vector_type(2))) unsigned uintx2;

#define SCALE_L2E 0.20823560929138437f  /* (1/sqrt(48)) * log2(e) */

#define BPH 128          // B*P*H = 8*4*4
#define SEQ 1024
#define DMODEL 192
#define DHEAD 48
#define MROWS 32768      // B*P*N
#define RESCALE_THR 11.5f  /* log2 domain ~ e^8 */

#define ZERO16 {0.f,0.f,0.f,0.f,0.f,0.f,0.f,0.f,0.f,0.f,0.f,0.f,0.f,0.f,0.f,0.f}

__device__ __forceinline__ unsigned short bfu(float f) {
    return __bfloat16_as_ushort(__float2bfloat16(f));
}
__device__ __forceinline__ unsigned pk2(float lo, float hi) {
    return (unsigned)bfu(lo) | ((unsigned)bfu(hi) << 16);
}

// ---------------------------------------------------------------------------
// Kernel 1: QKV projection. C[m, c] = sum_k x[m,k] * w_qkv[c,k] + b_qkv[c]
// 64x64 tile per block, 4 waves x (16 rows x 64 cols) each.
// LDS staging packed as b64 writes (cvt_pk pairs).
// q (scaled by SCALE*log2e) / k -> [bph][n][48] bf16.
// v -> [bph][d][n] bf16, transposed through LDS for coalesced stores.
// ---------------------------------------------------------------------------
__global__ __launch_bounds__(256) void qkv_kernel(
    const float* __restrict__ x,
    const float* __restrict__ w_qkv,
    const float* __restrict__ b_qkv,
    unsigned short* __restrict__ q_ws,
    unsigned short* __restrict__ k_ws,
    unsigned short* __restrict__ vt_ws)
{
    __shared__ unsigned short a_lds[64 * 200];
    __shared__ unsigned short w_lds[64 * 200];
    const int t = threadIdx.x;
    const int m0 = blockIdx.x * 64;
    const int n0 = blockIdx.y * 64;

    // stage A tile (fp32 -> bf16): 64 rows x 192 cols = 3072 float4
    #pragma unroll
    for (int i = 0; i < 12; ++i) {
        int idx = t + i * 256;
        int row = idx / 48, c4 = idx % 48;
        float4 v = *reinterpret_cast<const float4*>(x + (size_t)(m0 + row) * DMODEL + c4 * 4);
        uintx2 p; p.x = pk2(v.x, v.y); p.y = pk2(v.z, v.w);
        *reinterpret_cast<uintx2*>(&a_lds[row * 200 + c4 * 4]) = p;
    }
    #pragma unroll
    for (int i = 0; i < 12; ++i) {
        int idx = t + i * 256;
        int row = idx / 48, c4 = idx % 48;
        float4 v = *reinterpret_cast<const float4*>(w_qkv + (size_t)(n0 + row) * DMODEL + c4 * 4);
        uintx2 p; p.x = pk2(v.x, v.y); p.y = pk2(v.z, v.w);
        *reinterpret_cast<uintx2*>(&w_lds[row * 200 + c4 * 4]) = p;
    }
    __syncthreads();

    const int lane = t & 63, w = t >> 6;
    const int lrow = lane & 15, lhi = lane >> 4;

    floatx4 zf = {0.f, 0.f, 0.f, 0.f};
    floatx4 acc[4] = {zf, zf, zf, zf};

    #pragma unroll
    for (int ks = 0; ks < 6; ++ks) {
        bf16x8 af = *reinterpret_cast<const bf16x8*>(&a_lds[(w * 16 + lrow) * 200 + ks * 32 + lhi * 8]);
        #pragma unroll
        for (int cb = 0; cb < 4; ++cb) {
            bf16x8 bfr = *reinterpret_cast<const bf16x8*>(&w_lds[(cb * 16 + lrow) * 200 + ks * 32 + lhi * 8]);
            acc[cb] = __builtin_amdgcn_mfma_f32_16x16x32_bf16(af, bfr, acc[cb], 0, 0, 0);
        }
    }

    const int sec = n0 / 192;  // 0=q, 1=k, 2=v (uniform per block)
    if (sec == 2) {
        // V: transpose through LDS -> coalesced [d][n] stores
        __syncthreads();  // a_lds reads done; reuse as [64 c][72 pad] tile
        #pragma unroll
        for (int cb = 0; cb < 4; ++cb) {
            float bias = b_qkv[n0 + cb * 16 + lrow];
            #pragma unroll
            for (int r = 0; r < 4; ++r)
                a_lds[(cb * 16 + lrow) * 72 + (w * 16 + lhi * 4 + r)] = bfu(acc[cb][r] + bias);
        }
        __syncthreads();
        const int bp = m0 >> 10, nb = m0 & 1023;
        #pragma unroll
        for (int i = 0; i < 2; ++i) {
            int ch = t + i * 256;          // 512 chunks of 8 u16
            int c_local = ch >> 3, seg = ch & 7;
            int cc = n0 + c_local - 384;   // 0..191
            int h = cc / 48, dd = cc - h * 48;
            *reinterpret_cast<bf16x8*>(
                &vt_ws[((size_t)(bp * 4 + h) * DHEAD + dd) * SEQ + nb + seg * 8]) =
                *reinterpret_cast<const bf16x8*>(&a_lds[c_local * 72 + seg * 8]);
        }
    } else {
        #pragma unroll
        for (int cb = 0; cb < 4; ++cb) {
            int c = n0 + cb * 16 + lrow;          // 0..383
            int cc = c - sec * 192;               // 0..191
            int h = cc / 48, dd = cc - h * 48;
            float bias = b_qkv[c];
            #pragma unroll
            for (int r = 0; r < 4; ++r) {
                int m = m0 + w * 16 + lhi * 4 + r;
                float val = acc[cb][r] + bias;
                int bp = m >> 10, n = m & 1023;
                int bph = bp * 4 + h;
                if (sec == 0) {
                    q_ws[((size_t)bph * SEQ + n) * DHEAD + dd] = bfu(val * SCALE_L2E);
                } else {
                    k_ws[((size_t)bph * SEQ + n) * DHEAD + dd] = bfu(val);
                }
            }
        }
    }
}

// ---------------------------------------------------------------------------
// Kernel 2: flash attention, swapped-operand 32x32x16 MFMA, no LDS.
// One wave = 32 q rows of one (b,p,h). Block = 4 waves (same bph).
// XCD-swizzled dispatch (all q-chunks of a bph on one XCD's L2).
// K registers rotate: tile t+1's K loads issue right after QK^T(t) and land
// during softmax+PV. V staggered in two halves. Cross-half traffic uses the
// proven shfl_xor(32) + select form (permlane reverted pending direction A/B).
// ---------------------------------------------------------------------------
__global__ __launch_bounds__(256, 4) void attn_kernel(
    const unsigned short* __restrict__ q_ws,
    const unsigned short* __restrict__ k_ws,
    const unsigned short* __restrict__ vt_ws,
    unsigned short* __restrict__ z_ws)
{
    const int t = threadIdx.x, lane = t & 63, w = t >> 6;
    const int q31 = lane & 31, hi = lane >> 5;
    const int d = blockIdx.x;
    const int bph = (d & 7) | ((d >> 6) << 3);
    const int qc = (d >> 3) & 7;
    const int q0 = qc * 128 + w * 32;
    const int bp = bph >> 2, h = bph & 3;

    // Q fragments (3 k-slices of 16), pre-scaled by SCALE*log2e
    bf16x8 qf[3];
    {
        const unsigned short* qp = q_ws + ((size_t)bph * SEQ + q0 + q31) * DHEAD + hi * 8;
        #pragma unroll
        for (int ks = 0; ks < 3; ++ks)
            qf[ks] = *reinterpret_cast<const bf16x8*>(qp + ks * 16);
    }

    const unsigned short* kp  = k_ws + ((size_t)bph * SEQ + q31) * DHEAD + hi * 8;
    const int vrow1 = (32 + q31 > 47) ? 47 : (32 + q31);   // d rows 48..63 dup row 47, discarded
    const unsigned short* vp0 = vt_ws + ((size_t)bph * DHEAD + q31)  * (size_t)SEQ + hi * 8;
    const unsigned short* vp1 = vt_ws + ((size_t)bph * DHEAD + vrow1) * (size_t)SEQ + hi * 8;

    floatx16 oa0 = ZERO16, oa1 = ZERO16;
    float m_prev = -INFINITY, l_sum = 0.f;

    // preload K tile 0 (single rotating buffer)
    bf16x8 kf[6];
    #pragma unroll
    for (int ks = 0; ks < 3; ++ks) {
        kf[ks]     = *reinterpret_cast<const bf16x8*>(kp + ks * 16);
        kf[ks + 3] = *reinterpret_cast<const bf16x8*>(kp + 32 * DHEAD + ks * 16);
    }

    #pragma unroll 1
    for (int kt = 0; kt < 16; ++kt) {
        const int kt0 = kt * 64;

        // ---- V first half: covered by QK^T + softmax ----
        bf16x8 vf0[4];
        #pragma unroll
        for (int ksv = 0; ksv < 4; ++ksv)
            vf0[ksv] = *reinterpret_cast<const bf16x8*>(vp0 + kt0 + ksv * 16);

        // ---- S^T = K . Q^T ----
        floatx16 s0 = ZERO16, s1 = ZERO16;
        __builtin_amdgcn_s_setprio(1);
        #pragma unroll
        for (int ks = 0; ks < 3; ++ks) {
            s0 = __builtin_amdgcn_mfma_f32_32x32x16_bf16(kf[ks],     qf[ks], s0, 0, 0, 0);
            s1 = __builtin_amdgcn_mfma_f32_32x32x16_bf16(kf[ks + 3], qf[ks], s1, 0, 0, 0);
        }
        __builtin_amdgcn_s_setprio(0);

        // ---- rotate-prefetch next tile's K into the same regs (lands during
        //      softmax+PV; WAR on kf vs QK^T is register-dependency ordered) ----
        {
            const unsigned short* kpn = kp + (size_t)(((kt + 1) & 15) * 64) * DHEAD;
            #pragma unroll
            for (int ks = 0; ks < 3; ++ks) {
                kf[ks]     = *reinterpret_cast<const bf16x8*>(kpn + ks * 16);
                kf[ks + 3] = *reinterpret_cast<const bf16x8*>(kpn + 32 * DHEAD + ks * 16);
            }
        }

        // ---- V second half: covered by softmax ----
        bf16x8 vf1[4];
        #pragma unroll
        for (int ksv = 0; ksv < 4; ++ksv)
            vf1[ksv] = *reinterpret_cast<const bf16x8*>(vp1 + kt0 + ksv * 16);

        // ---- tree max (depth 5) + cross-half shfl ----
        float a[8];
        #pragma unroll
        for (int u = 0; u < 8; ++u)
            a[u] = fmaxf(fmaxf(s0[2*u], s0[2*u+1]), fmaxf(s1[2*u], s1[2*u+1]));
        float m01 = fmaxf(fmaxf(a[0], a[1]), fmaxf(a[2], a[3]));
        float m23 = fmaxf(fmaxf(a[4], a[5]), fmaxf(a[6], a[7]));
        float tmax = fmaxf(m01, m23);
        tmax = fmaxf(tmax, __shfl_xor(tmax, 32, 64));

        if (!__all((int)(tmax <= m_prev + RESCALE_THR))) {
            const float mnew = fmaxf(m_prev, tmax);
            const float scale = exp2f(m_prev - mnew);
            m_prev = mnew;
            l_sum *= scale;
            oa0 = oa0 * scale;
            oa1 = oa1 * scale;
        }
        const float mref = m_prev;

        // ---- exp + pack (split accumulators) ----
        unsigned W0[8], W1[8];
        float tsA = 0.f, tsB = 0.f;
        #pragma unroll
        for (int u = 0; u < 8; ++u) {
            float e0 = __builtin_amdgcn_exp2f(s0[2*u]   - mref);
            float e1 = __builtin_amdgcn_exp2f(s0[2*u+1] - mref);
            tsA += e0 + e1;
            W0[u] = pk2(e0, e1);
        }
        #pragma unroll
        for (int u = 0; u < 8; ++u) {
            float e0 = __builtin_amdgcn_exp2f(s1[2*u]   - mref);
            float e1 = __builtin_amdgcn_exp2f(s1[2*u+1] - mref);
            tsB += e0 + e1;
            W1[u] = pk2(e0, e1);
        }
        float ts = tsA + tsB;
        ts += __shfl_xor(ts, 32, 64);
        l_sum += ts;

        // ---- cross-half P redistribution: proven shfl_xor + select form ----
        unsigned X0[8], X1[8];
        #pragma unroll
        for (int u = 0; u < 8; ++u) X0[u] = __shfl_xor(W0[u], 32, 64);
        #pragma unroll
        for (int u = 0; u < 8; ++u) X1[u] = __shfl_xor(W1[u], 32, 64);

        // ---- O^T += Vt . P^T ----
        union U { bf16x8 v; unsigned wd[4]; };
        __builtin_amdgcn_s_setprio(1);
        {
            U pa;
            pa.wd[0] = hi ? X0[2] : W0[0];
            pa.wd[1] = hi ? X0[3] : W0[1];
            pa.wd[2] = hi ? W0[2] : X0[0];
            pa.wd[3] = hi ? W0[3] : X0[1];
            oa0 = __builtin_amdgcn_mfma_f32_32x32x16_bf16(vf0[0], pa.v, oa0, 0, 0, 0);
            oa1 = __builtin_amdgcn_mfma_f32_32x32x16_bf16(vf1[0], pa.v, oa1, 0, 0, 0);
        }
        {
            U pb;
            pb.wd[0] = hi ? X0[6] : W0[4];
            pb.wd[1] = hi ? X0[7] : W0[5];
            pb.wd[2] = hi ? W0[6] : X0[4];
            pb.wd[3] = hi ? W0[7] : X0[5];
            oa0 = __builtin_amdgcn_mfma_f32_32x32x16_bf16(vf0[1], pb.v, oa0, 0, 0, 0);
            oa1 = __builtin_amdgcn_mfma_f32_32x32x16_bf16(vf1[1], pb.v, oa1, 0, 0, 0);
        }
        {
            U pc;
            pc.wd[0] = hi ? X1[2] : W1[0];
            pc.wd[1] = hi ? X1[3] : W1[1];
            pc.wd[2] = hi ? W1[2] : X1[0];
            pc.wd[3] = hi ? W1[3] : X1[1];
            oa0 = __builtin_amdgcn_mfma_f32_32x32x16_bf16(vf0[2], pc.v, oa0, 0, 0, 0);
            oa1 = __builtin_amdgcn_mfma_f32_32x32x16_bf16(vf1[2], pc.v, oa1, 0, 0, 0);
        }
        {
            U pd;
            pd.wd[0] = hi ? X1[6] : W1[4];
            pd.wd[1] = hi ? X1[7] : W1[5];
            pd.wd[2] = hi ? W1[6] : X1[4];
            pd.wd[3] = hi ? W1[7] : X1[5];
            oa0 = __builtin_amdgcn_mfma_f32_32x32x16_bf16(vf0[3], pd.v, oa0, 0, 0, 0);
            oa1 = __builtin_amdgcn_mfma_f32_32x32x16_bf16(vf1[3], pd.v, oa1, 0, 0, 0);
        }
        __builtin_amdgcn_s_setprio(0);
    }

    // ---- normalize + write z [bp][n][192] bf16 (paired u32 stores) ----
    const float inv = 1.0f / l_sum;
    unsigned* zp = reinterpret_cast<unsigned*>(
        z_ws + ((size_t)bp * SEQ + q0 + q31) * DMODEL + h * DHEAD);
    #pragma unroll
    for (int u = 0; u < 8; ++u) {
        int dd = 2 * (u & 1) + 8 * (u >> 1) + 4 * hi;       // d, d+1
        zp[dd >> 1] = pk2(oa0[2*u] * inv, oa0[2*u+1] * inv);
    }
    #pragma unroll
    for (int u = 0; u < 4; ++u) {
        int dd = 32 + 2 * (u & 1) + 8 * (u >> 1) + 4 * hi;  // 32..47 only
        zp[dd >> 1] = pk2(oa1[2*u] * inv, oa1[2*u+1] * inv);
    }
}

// ---------------------------------------------------------------------------
// Kernel 3: output projection. out[m, c] = sum_k z[m,k] * w_proj[c,k] + b_proj[c]
// ---------------------------------------------------------------------------
__global__ __launch_bounds__(256) void proj_kernel(
    const unsigned short* __restrict__ z_ws,
    const float* __restrict__ w_proj,
    const float* __restrict__ b_proj,
    float* __restrict__ out)
{
    __shared__ unsigned short a_lds[64 * 200];
    __shared__ unsigned short w_lds[64 * 200];
    const int t = threadIdx.x;
    const int m0 = blockIdx.x * 64;
    const int n0 = blockIdx.y * 64;

    for (int i = t; i < 1536; i += 256) {
        int row = i / 24, c8 = i % 24;
        *reinterpret_cast<bf16x8*>(&a_lds[row * 200 + c8 * 8]) =
            *reinterpret_cast<const bf16x8*>(&z_ws[(size_t)(m0 + row) * DMODEL + c8 * 8]);
    }
    #pragma unroll
    for (int i = 0; i < 12; ++i) {
        int idx = t + i * 256;
        int row = idx / 48, c4 = idx % 48;
        float4 v = *reinterpret_cast<const float4*>(w_proj + (size_t)(n0 + row) * DMODEL + c4 * 4);
        uintx2 p; p.x = pk2(v.x, v.y); p.y = pk2(v.z, v.w);
        *reinterpret_cast<uintx2*>(&w_lds[row * 200 + c4 * 4]) = p;
    }
    __syncthreads();

    const int lane = t & 63, w = t >> 6;
    const int lrow = lane & 15, lhi = lane >> 4;

    floatx4 zf = {0.f, 0.f, 0.f, 0.f};
    floatx4 acc[4] = {zf, zf, zf, zf};

    #pragma unroll
    for (int ks = 0; ks < 6; ++ks) {
        bf16x8 af = *reinterpret_cast<const bf16x8*>(&a_lds[(w * 16 + lrow) * 200 + ks * 32 + lhi * 8]);
        #pragma unroll
        for (int cb = 0; cb < 4; ++cb) {
            bf16x8 bfr = *reinterpret_cast<const bf16x8*>(&w_lds[(cb * 16 + lrow) * 200 + ks * 32 + lhi * 8]);
            acc[cb] = __builtin_amdgcn_mfma_f32_16x16x32_bf16(af, bfr, acc[cb], 0, 0, 0);
        }
    }

    #pragma unroll
    for (int cb = 0; cb < 4; ++cb) {
        int c = n0 + cb * 16 + lrow;
        float bias = b_proj[c];
        #pragma unroll
        for (int r = 0; r < 4; ++r) {
            int m = m0 + w * 16 + lhi * 4 + r;
            out[(size_t)m * DMODEL + c] = acc[cb][r] + bias;
        }
    }
}

// ---------------------------------------------------------------------------
extern "C" void kernel_launch(void* const* d_in, const int* in_sizes, int n_in,
                              void* d_out, int out_size, void* d_ws, size_t ws_size,
                              hipStream_t stream) {
    const float* x      = (const float*)d_in[0];
    const float* w_qkv  = (const float*)d_in[1];
    const float* b_qkv  = (const float*)d_in[2];
    const float* w_proj = (const float*)d_in[3];
    const float* b_proj = (const float*)d_in[4];
    float* out = (float*)d_out;

    unsigned short* q_ws  = (unsigned short*)d_ws;
    unsigned short* k_ws  = q_ws  + (size_t)BPH * SEQ * DHEAD;   // 6.29M elems each
    unsigned short* vt_ws = k_ws  + (size_t)BPH * SEQ * DHEAD;
    unsigned short* z_ws  = vt_ws + (size_t)BPH * DHEAD * SEQ;
    // total ws usage: 4 * 12.58 MB = 50.3 MB

    qkv_kernel<<<dim3(512, 9), 256, 0, stream>>>(x, w_qkv, b_qkv, q_ws, k_ws, vt_ws);
    attn_kernel<<<1024, 256, 0, stream>>>(q_ws, k_ws, vt_ws, z_ws);
    proj_kernel<<<dim3(512, 3), 256, 0, stream>>>(z_ws, w_proj, b_proj, out);
}